// Round 1
// baseline (2508.872 us; speedup 1.0000x reference)
//
#include <hip/hip_runtime.h>

#define N_NODES 50000
#define N_EDGES 800000
#define N_FEAT 128
#define N_HID 128
#define N_CLS 40
#define BN_EPS 1e-5f

// ---------------------------------------------------------------------------
// K1: degree histogram. 800K atomics, trivial.
// ---------------------------------------------------------------------------
__global__ __launch_bounds__(256) void deg_kernel(const int* __restrict__ dst,
                                                  float* __restrict__ deg) {
    int e = blockIdx.x * 256 + threadIdx.x;
    if (e < N_EDGES) atomicAdd(&deg[dst[e]], 1.0f);
}

// ---------------------------------------------------------------------------
// K2: layer-1 scatter: agg1[dst] += x[src], 128 floats/row.
// 32 lanes per edge, float4 per lane.
// ---------------------------------------------------------------------------
__global__ __launch_bounds__(256) void scatter1_kernel(const int* __restrict__ src,
                                                       const int* __restrict__ dst,
                                                       const float* __restrict__ x,
                                                       float* __restrict__ agg1) {
    int t = blockIdx.x * 256 + threadIdx.x;
    int e = t >> 5;
    int lane = t & 31;
    if (e >= N_EDGES) return;
    int s = src[e];
    int d = dst[e];
    float4 v = ((const float4*)x)[s * 32 + lane];
    float* p = agg1 + (size_t)d * 128 + lane * 4;
    atomicAdd(p + 0, v.x);
    atomicAdd(p + 1, v.y);
    atomicAdd(p + 2, v.z);
    atomicAdd(p + 3, v.w);
}

// ---------------------------------------------------------------------------
// K3: fused layer 1:  h = BN(ReLU(inv_deg * (agg1 @ W1l^T) + b1 + x @ W1r^T))
// grid (ceil(N/32), 2): blockIdx.y picks 64-column half. 4 waves x 8 rows.
// Weights transposed in LDS with (c+k)&63 rotation swizzle: conflict-free
// staging writes AND main-loop reads. Exactly 64 KB LDS.
// ---------------------------------------------------------------------------
__global__ __launch_bounds__(256) void layer1_kernel(
    const float* __restrict__ x, const float* __restrict__ agg1,
    const float* __restrict__ deg, const float* __restrict__ W1l,
    const float* __restrict__ b1, const float* __restrict__ W1r,
    const float* __restrict__ gamma, const float* __restrict__ beta,
    const float* __restrict__ rmean, const float* __restrict__ rvar,
    float* __restrict__ h) {
    __shared__ float Wt1[128][64];
    __shared__ float Wt2[128][64];
    const int t = threadIdx.x;
    const int cbase = blockIdx.y << 6;
    for (int i = t; i < 128 * 64; i += 256) {
        int c = i >> 7;           // 0..63 local col
        int k = i & 127;          // feature idx (coalesced global read)
        int cs = (c + k) & 63;    // rotation swizzle
        Wt1[k][cs] = W1l[(cbase + c) * 128 + k];
        Wt2[k][cs] = W1r[(cbase + c) * 128 + k];
    }
    __syncthreads();

    const int wave = t >> 6;
    const int lane = t & 63;
    const int c = cbase + lane;
    int r0 = blockIdx.x * 32 + wave * 8;
    r0 = __builtin_amdgcn_readfirstlane(r0);  // provably uniform -> s_load rows
    if (r0 >= N_NODES) return;

    float acc1[8], acc2[8];
#pragma unroll
    for (int rr = 0; rr < 8; ++rr) { acc1[rr] = 0.f; acc2[rr] = 0.f; }

    int ridx[8];
#pragma unroll
    for (int rr = 0; rr < 8; ++rr) ridx[rr] = (r0 + rr < N_NODES) ? r0 + rr : N_NODES - 1;

    const float4* x4 = (const float4*)x;
    const float4* a4 = (const float4*)agg1;

    for (int k4 = 0; k4 < 32; ++k4) {
        float4 xr[8], ar[8];
#pragma unroll
        for (int rr = 0; rr < 8; ++rr) {
            xr[rr] = x4[ridx[rr] * 32 + k4];
            ar[rr] = a4[ridx[rr] * 32 + k4];
        }
#pragma unroll
        for (int j = 0; j < 4; ++j) {
            int k = k4 * 4 + j;
            float w1 = Wt1[k][(lane + k) & 63];
            float w2 = Wt2[k][(lane + k) & 63];
#pragma unroll
            for (int rr = 0; rr < 8; ++rr) {
                float av = (j == 0) ? ar[rr].x : (j == 1) ? ar[rr].y : (j == 2) ? ar[rr].z : ar[rr].w;
                float xv = (j == 0) ? xr[rr].x : (j == 1) ? xr[rr].y : (j == 2) ? xr[rr].z : xr[rr].w;
                acc1[rr] = fmaf(av, w1, acc1[rr]);
                acc2[rr] = fmaf(xv, w2, acc2[rr]);
            }
        }
    }

    float scale = gamma[c] * rsqrtf(rvar[c] + BN_EPS);
    float shift = fmaf(-rmean[c], scale, beta[c]);
    float bias = b1[c];
#pragma unroll
    for (int rr = 0; rr < 8; ++rr) {
        int r = r0 + rr;
        if (r < N_NODES) {
            float idg = 1.0f / fmaxf(deg[r], 1.0f);
            float pre = fmaf(idg, acc1[rr], bias) + acc2[rr];
            float hv = fmaxf(pre, 0.0f);
            h[(size_t)r * 128 + c] = fmaf(hv, scale, shift);
        }
    }
}

// ---------------------------------------------------------------------------
// K4: z2 = h @ W2l^T   (50000x128 @ 128x40)
// Same structure; W staged [128][64] with rotation swizzle (32 KB).
// Lanes 40..63 idle in the epilogue (wasted but memory-trivial kernel).
// ---------------------------------------------------------------------------
__global__ __launch_bounds__(256) void z2_kernel(const float* __restrict__ h,
                                                 const float* __restrict__ W2l,
                                                 float* __restrict__ z2) {
    __shared__ float Wt[128][64];
    const int t = threadIdx.x;
    for (int i = t; i < 128 * 40; i += 256) {
        int c = i >> 7;  // 0..39
        int k = i & 127;
        Wt[k][(c + k) & 63] = W2l[c * 128 + k];
    }
    __syncthreads();

    const int wave = t >> 6;
    const int lane = t & 63;
    const int cl = (lane < 40) ? lane : 0;
    int r0 = blockIdx.x * 32 + wave * 8;
    r0 = __builtin_amdgcn_readfirstlane(r0);
    if (r0 >= N_NODES) return;

    float acc[8];
#pragma unroll
    for (int rr = 0; rr < 8; ++rr) acc[rr] = 0.f;
    int ridx[8];
#pragma unroll
    for (int rr = 0; rr < 8; ++rr) ridx[rr] = (r0 + rr < N_NODES) ? r0 + rr : N_NODES - 1;

    const float4* h4 = (const float4*)h;
    for (int k4 = 0; k4 < 32; ++k4) {
        float4 hr[8];
#pragma unroll
        for (int rr = 0; rr < 8; ++rr) hr[rr] = h4[ridx[rr] * 32 + k4];
#pragma unroll
        for (int j = 0; j < 4; ++j) {
            int k = k4 * 4 + j;
            float w = Wt[k][(cl + k) & 63];
#pragma unroll
            for (int rr = 0; rr < 8; ++rr) {
                float hv = (j == 0) ? hr[rr].x : (j == 1) ? hr[rr].y : (j == 2) ? hr[rr].z : hr[rr].w;
                acc[rr] = fmaf(hv, w, acc[rr]);
            }
        }
    }
    if (lane < 40) {
#pragma unroll
        for (int rr = 0; rr < 8; ++rr) {
            int r = r0 + rr;
            if (r < N_NODES) z2[(size_t)r * 40 + lane] = acc[rr];
        }
    }
}

// ---------------------------------------------------------------------------
// K5: layer-2 scatter: agg2[dst] += z2[src], 40 floats/row. One wave = 1 edge.
// ---------------------------------------------------------------------------
__global__ __launch_bounds__(256) void scatter2_kernel(const int* __restrict__ src,
                                                       const int* __restrict__ dst,
                                                       const float* __restrict__ z2,
                                                       float* __restrict__ agg2) {
    int t = blockIdx.x * 256 + threadIdx.x;
    int e = t >> 6;
    int lane = t & 63;
    if (e >= N_EDGES || lane >= 40) return;
    int s = src[e];
    int d = dst[e];
    atomicAdd(&agg2[(size_t)d * 40 + lane], z2[(size_t)s * 40 + lane]);
}

// ---------------------------------------------------------------------------
// K6: out = inv_deg * agg2 + b2 + h @ W2r^T
// ---------------------------------------------------------------------------
__global__ __launch_bounds__(256) void final_kernel(const float* __restrict__ h,
                                                    const float* __restrict__ W2r,
                                                    const float* __restrict__ agg2,
                                                    const float* __restrict__ deg,
                                                    const float* __restrict__ b2,
                                                    float* __restrict__ out) {
    __shared__ float Wt[128][64];
    const int t = threadIdx.x;
    for (int i = t; i < 128 * 40; i += 256) {
        int c = i >> 7;
        int k = i & 127;
        Wt[k][(c + k) & 63] = W2r[c * 128 + k];
    }
    __syncthreads();

    const int wave = t >> 6;
    const int lane = t & 63;
    const int cl = (lane < 40) ? lane : 0;
    int r0 = blockIdx.x * 32 + wave * 8;
    r0 = __builtin_amdgcn_readfirstlane(r0);
    if (r0 >= N_NODES) return;

    float acc[8];
#pragma unroll
    for (int rr = 0; rr < 8; ++rr) acc[rr] = 0.f;
    int ridx[8];
#pragma unroll
    for (int rr = 0; rr < 8; ++rr) ridx[rr] = (r0 + rr < N_NODES) ? r0 + rr : N_NODES - 1;

    const float4* h4 = (const float4*)h;
    for (int k4 = 0; k4 < 32; ++k4) {
        float4 hr[8];
#pragma unroll
        for (int rr = 0; rr < 8; ++rr) hr[rr] = h4[ridx[rr] * 32 + k4];
#pragma unroll
        for (int j = 0; j < 4; ++j) {
            int k = k4 * 4 + j;
            float w = Wt[k][(cl + k) & 63];
#pragma unroll
            for (int rr = 0; rr < 8; ++rr) {
                float hv = (j == 0) ? hr[rr].x : (j == 1) ? hr[rr].y : (j == 2) ? hr[rr].z : hr[rr].w;
                acc[rr] = fmaf(hv, w, acc[rr]);
            }
        }
    }
    if (lane < 40) {
        float bias = b2[lane];
#pragma unroll
        for (int rr = 0; rr < 8; ++rr) {
            int r = r0 + rr;
            if (r < N_NODES) {
                float idg = 1.0f / fmaxf(deg[r], 1.0f);
                out[(size_t)r * 40 + lane] =
                    fmaf(idg, agg2[(size_t)r * 40 + lane], bias) + acc[rr];
            }
        }
    }
}

// ---------------------------------------------------------------------------
// Launch. ws layout (floats):
//   deg   [0, 50048)
//   agg1  [50048, +6400000)
//   agg2  next 2000000        (deg+agg1+agg2 zeroed in one memset)
//   h     next 6400000        (fully overwritten)
//   z2    next 2000000        (fully overwritten)
// Total ~67.4 MB.
// ---------------------------------------------------------------------------
extern "C" void kernel_launch(void* const* d_in, const int* in_sizes, int n_in,
                              void* d_out, int out_size, void* d_ws, size_t ws_size,
                              hipStream_t stream) {
    const float* x     = (const float*)d_in[0];
    const int*   ei    = (const int*)d_in[1];
    const float* W1l   = (const float*)d_in[2];
    const float* b1    = (const float*)d_in[3];
    const float* W1r   = (const float*)d_in[4];
    const float* gamma = (const float*)d_in[5];
    const float* beta  = (const float*)d_in[6];
    const float* rmean = (const float*)d_in[7];
    const float* rvar  = (const float*)d_in[8];
    const float* W2l   = (const float*)d_in[9];
    const float* b2    = (const float*)d_in[10];
    const float* W2r   = (const float*)d_in[11];
    float* out = (float*)d_out;

    float* ws   = (float*)d_ws;
    float* deg  = ws;
    float* agg1 = deg + 50048;
    float* agg2 = agg1 + 6400000;
    float* h    = agg2 + 2000000;
    float* z2   = h + 6400000;

    const int* src = ei;
    const int* dst = ei + N_EDGES;

    // zero deg + agg1 + agg2 in one shot (ws is poisoned 0xAA before each call)
    hipMemsetAsync(deg, 0, (size_t)(50048 + 6400000 + 2000000) * sizeof(float), stream);

    deg_kernel<<<(N_EDGES + 255) / 256, 256, 0, stream>>>(dst, deg);

    scatter1_kernel<<<(N_EDGES * 32) / 256, 256, 0, stream>>>(src, dst, x, agg1);

    dim3 g1((N_NODES + 31) / 32, 2);
    layer1_kernel<<<g1, 256, 0, stream>>>(x, agg1, deg, W1l, b1, W1r, gamma, beta,
                                          rmean, rvar, h);

    z2_kernel<<<(N_NODES + 31) / 32, 256, 0, stream>>>(h, W2l, z2);

    scatter2_kernel<<<(N_EDGES * 64) / 256, 256, 0, stream>>>(src, dst, z2, agg2);

    final_kernel<<<(N_NODES + 31) / 32, 256, 0, stream>>>(h, W2r, agg2, deg, b2, out);
}

// Round 2
// 1067.531 us; speedup vs baseline: 2.3502x; 2.3502x over previous
//
#include <hip/hip_runtime.h>

#define N_NODES 50000
#define N_EDGES 800000
#define N_FEAT 128
#define N_HID 128
#define N_CLS 40
#define BN_EPS 1e-5f

#define SCAN_BLOCKS ((N_NODES + 255) / 256)  // 196

// ---------------------------------------------------------------------------
// K1: int degree histogram.
// ---------------------------------------------------------------------------
__global__ __launch_bounds__(256) void deg_kernel(const int* __restrict__ dst,
                                                  int* __restrict__ deg_i) {
    int e = blockIdx.x * 256 + threadIdx.x;
    if (e < N_EDGES) atomicAdd(&deg_i[dst[e]], 1);
}

// ---------------------------------------------------------------------------
// Scan phase A: per-block exclusive scan of deg, block totals out.
// ---------------------------------------------------------------------------
__global__ __launch_bounds__(256) void scanA_kernel(const int* __restrict__ deg_i,
                                                    int* __restrict__ row_ptr,
                                                    int* __restrict__ blk_sum) {
    __shared__ int tmp[256];
    int t = threadIdx.x;
    int i = blockIdx.x * 256 + t;
    int v = (i < N_NODES) ? deg_i[i] : 0;
    tmp[t] = v;
    __syncthreads();
    for (int off = 1; off < 256; off <<= 1) {
        int a = (t >= off) ? tmp[t - off] : 0;
        __syncthreads();
        if (t >= off) tmp[t] += a;
        __syncthreads();
    }
    if (i < N_NODES) row_ptr[i] = tmp[t] - v;  // local exclusive
    if (t == 255) blk_sum[blockIdx.x] = tmp[255];
}

// ---------------------------------------------------------------------------
// Scan phase B: single block scans the 196 block sums (exclusive).
// ---------------------------------------------------------------------------
__global__ __launch_bounds__(256) void scanB_kernel(const int* __restrict__ blk_sum,
                                                    int* __restrict__ blk_off) {
    __shared__ int tmp[256];
    int t = threadIdx.x;
    int v = (t < SCAN_BLOCKS) ? blk_sum[t] : 0;
    tmp[t] = v;
    __syncthreads();
    for (int off = 1; off < 256; off <<= 1) {
        int a = (t >= off) ? tmp[t - off] : 0;
        __syncthreads();
        if (t >= off) tmp[t] += a;
        __syncthreads();
    }
    if (t < SCAN_BLOCKS) blk_off[t] = tmp[t] - v;
}

// ---------------------------------------------------------------------------
// Scan phase C: add block offsets; finalize row_ptr[N]=E.
// ---------------------------------------------------------------------------
__global__ __launch_bounds__(256) void scanC_kernel(int* __restrict__ row_ptr,
                                                    const int* __restrict__ blk_off) {
    int i = blockIdx.x * 256 + threadIdx.x;
    if (i < N_NODES) row_ptr[i] += blk_off[blockIdx.x];
    if (i == 0) row_ptr[N_NODES] = N_EDGES;
}

// ---------------------------------------------------------------------------
// CSR fill: csr_src grouped by dst. 800K atomics over 50K cursors.
// ---------------------------------------------------------------------------
__global__ __launch_bounds__(256) void fill_kernel(const int* __restrict__ src,
                                                   const int* __restrict__ dst,
                                                   const int* __restrict__ row_ptr,
                                                   int* __restrict__ cursor,
                                                   int* __restrict__ csr_src) {
    int e = blockIdx.x * 256 + threadIdx.x;
    if (e >= N_EDGES) return;
    int d = dst[e];
    int pos = atomicAdd(&cursor[d], 1);
    csr_src[row_ptr[d] + pos] = src[e];
}

// ---------------------------------------------------------------------------
// Gather-aggregate layer 1: wave per node, float2 per lane (128 floats).
// Coalesced 512 B per edge; x is LLC-resident. No atomics, no pre-zero.
// ---------------------------------------------------------------------------
__global__ __launch_bounds__(256) void gather1_kernel(const int* __restrict__ csr_src,
                                                      const int* __restrict__ row_ptr,
                                                      const float* __restrict__ x,
                                                      float* __restrict__ agg1) {
    int gid = blockIdx.x * 4 + (threadIdx.x >> 6);
    gid = __builtin_amdgcn_readfirstlane(gid);
    int lane = threadIdx.x & 63;
    if (gid >= N_NODES) return;
    int beg = row_ptr[gid];
    int end = row_ptr[gid + 1];
    const float2* x2 = (const float2*)x;
    float2 acc = {0.f, 0.f};
    int e = beg;
    for (; e + 1 < end; e += 2) {
        int s0 = csr_src[e];
        int s1 = csr_src[e + 1];
        float2 v0 = x2[(size_t)s0 * 64 + lane];
        float2 v1 = x2[(size_t)s1 * 64 + lane];
        acc.x += v0.x + v1.x;
        acc.y += v0.y + v1.y;
    }
    if (e < end) {
        int s = csr_src[e];
        float2 v = x2[(size_t)s * 64 + lane];
        acc.x += v.x;
        acc.y += v.y;
    }
    ((float2*)agg1)[(size_t)gid * 64 + lane] = acc;
}

// ---------------------------------------------------------------------------
// Gather-aggregate layer 2: wave per node, lanes 0..39 (40 floats).
// ---------------------------------------------------------------------------
__global__ __launch_bounds__(256) void gather2_kernel(const int* __restrict__ csr_src,
                                                      const int* __restrict__ row_ptr,
                                                      const float* __restrict__ z2,
                                                      float* __restrict__ agg2) {
    int gid = blockIdx.x * 4 + (threadIdx.x >> 6);
    gid = __builtin_amdgcn_readfirstlane(gid);
    int lane = threadIdx.x & 63;
    if (gid >= N_NODES) return;
    int beg = row_ptr[gid];
    int end = row_ptr[gid + 1];
    float acc = 0.f;
    int e = beg;
    for (; e + 1 < end; e += 2) {
        int s0 = csr_src[e];
        int s1 = csr_src[e + 1];
        if (lane < 40)
            acc += z2[(size_t)s0 * 40 + lane] + z2[(size_t)s1 * 40 + lane];
    }
    if (e < end) {
        int s = csr_src[e];
        if (lane < 40) acc += z2[(size_t)s * 40 + lane];
    }
    if (lane < 40) agg2[(size_t)gid * 40 + lane] = acc;
}

// ---------------------------------------------------------------------------
// K3: fused layer 1:  h = BN(ReLU(inv_deg * (agg1 @ W1l^T) + b1 + x @ W1r^T))
// ---------------------------------------------------------------------------
__global__ __launch_bounds__(256) void layer1_kernel(
    const float* __restrict__ x, const float* __restrict__ agg1,
    const int* __restrict__ deg_i, const float* __restrict__ W1l,
    const float* __restrict__ b1, const float* __restrict__ W1r,
    const float* __restrict__ gamma, const float* __restrict__ beta,
    const float* __restrict__ rmean, const float* __restrict__ rvar,
    float* __restrict__ h) {
    __shared__ float Wt1[128][64];
    __shared__ float Wt2[128][64];
    const int t = threadIdx.x;
    const int cbase = blockIdx.y << 6;
    for (int i = t; i < 128 * 64; i += 256) {
        int c = i >> 7;
        int k = i & 127;
        int cs = (c + k) & 63;
        Wt1[k][cs] = W1l[(cbase + c) * 128 + k];
        Wt2[k][cs] = W1r[(cbase + c) * 128 + k];
    }
    __syncthreads();

    const int wave = t >> 6;
    const int lane = t & 63;
    const int c = cbase + lane;
    int r0 = blockIdx.x * 32 + wave * 8;
    r0 = __builtin_amdgcn_readfirstlane(r0);
    if (r0 >= N_NODES) return;

    float acc1[8], acc2[8];
#pragma unroll
    for (int rr = 0; rr < 8; ++rr) { acc1[rr] = 0.f; acc2[rr] = 0.f; }

    int ridx[8];
#pragma unroll
    for (int rr = 0; rr < 8; ++rr) ridx[rr] = (r0 + rr < N_NODES) ? r0 + rr : N_NODES - 1;

    const float4* x4 = (const float4*)x;
    const float4* a4 = (const float4*)agg1;

    for (int k4 = 0; k4 < 32; ++k4) {
        float4 xr[8], ar[8];
#pragma unroll
        for (int rr = 0; rr < 8; ++rr) {
            xr[rr] = x4[ridx[rr] * 32 + k4];
            ar[rr] = a4[ridx[rr] * 32 + k4];
        }
#pragma unroll
        for (int j = 0; j < 4; ++j) {
            int k = k4 * 4 + j;
            float w1 = Wt1[k][(lane + k) & 63];
            float w2 = Wt2[k][(lane + k) & 63];
#pragma unroll
            for (int rr = 0; rr < 8; ++rr) {
                float av = (j == 0) ? ar[rr].x : (j == 1) ? ar[rr].y : (j == 2) ? ar[rr].z : ar[rr].w;
                float xv = (j == 0) ? xr[rr].x : (j == 1) ? xr[rr].y : (j == 2) ? xr[rr].z : xr[rr].w;
                acc1[rr] = fmaf(av, w1, acc1[rr]);
                acc2[rr] = fmaf(xv, w2, acc2[rr]);
            }
        }
    }

    float scale = gamma[c] * rsqrtf(rvar[c] + BN_EPS);
    float shift = fmaf(-rmean[c], scale, beta[c]);
    float bias = b1[c];
#pragma unroll
    for (int rr = 0; rr < 8; ++rr) {
        int r = r0 + rr;
        if (r < N_NODES) {
            float idg = 1.0f / fmaxf((float)deg_i[r], 1.0f);
            float pre = fmaf(idg, acc1[rr], bias) + acc2[rr];
            float hv = fmaxf(pre, 0.0f);
            h[(size_t)r * 128 + c] = fmaf(hv, scale, shift);
        }
    }
}

// ---------------------------------------------------------------------------
// K4: z2 = h @ W2l^T   (50000x128 @ 128x40)
// ---------------------------------------------------------------------------
__global__ __launch_bounds__(256) void z2_kernel(const float* __restrict__ h,
                                                 const float* __restrict__ W2l,
                                                 float* __restrict__ z2) {
    __shared__ float Wt[128][64];
    const int t = threadIdx.x;
    for (int i = t; i < 128 * 40; i += 256) {
        int c = i >> 7;
        int k = i & 127;
        Wt[k][(c + k) & 63] = W2l[c * 128 + k];
    }
    __syncthreads();

    const int wave = t >> 6;
    const int lane = t & 63;
    const int cl = (lane < 40) ? lane : 0;
    int r0 = blockIdx.x * 32 + wave * 8;
    r0 = __builtin_amdgcn_readfirstlane(r0);
    if (r0 >= N_NODES) return;

    float acc[8];
#pragma unroll
    for (int rr = 0; rr < 8; ++rr) acc[rr] = 0.f;
    int ridx[8];
#pragma unroll
    for (int rr = 0; rr < 8; ++rr) ridx[rr] = (r0 + rr < N_NODES) ? r0 + rr : N_NODES - 1;

    const float4* h4 = (const float4*)h;
    for (int k4 = 0; k4 < 32; ++k4) {
        float4 hr[8];
#pragma unroll
        for (int rr = 0; rr < 8; ++rr) hr[rr] = h4[ridx[rr] * 32 + k4];
#pragma unroll
        for (int j = 0; j < 4; ++j) {
            int k = k4 * 4 + j;
            float w = Wt[k][(cl + k) & 63];
#pragma unroll
            for (int rr = 0; rr < 8; ++rr) {
                float hv = (j == 0) ? hr[rr].x : (j == 1) ? hr[rr].y : (j == 2) ? hr[rr].z : hr[rr].w;
                acc[rr] = fmaf(hv, w, acc[rr]);
            }
        }
    }
    if (lane < 40) {
#pragma unroll
        for (int rr = 0; rr < 8; ++rr) {
            int r = r0 + rr;
            if (r < N_NODES) z2[(size_t)r * 40 + lane] = acc[rr];
        }
    }
}

// ---------------------------------------------------------------------------
// K6: out = inv_deg * agg2 + b2 + h @ W2r^T
// ---------------------------------------------------------------------------
__global__ __launch_bounds__(256) void final_kernel(const float* __restrict__ h,
                                                    const float* __restrict__ W2r,
                                                    const float* __restrict__ agg2,
                                                    const int* __restrict__ deg_i,
                                                    const float* __restrict__ b2,
                                                    float* __restrict__ out) {
    __shared__ float Wt[128][64];
    const int t = threadIdx.x;
    for (int i = t; i < 128 * 40; i += 256) {
        int c = i >> 7;
        int k = i & 127;
        Wt[k][(c + k) & 63] = W2r[c * 128 + k];
    }
    __syncthreads();

    const int wave = t >> 6;
    const int lane = t & 63;
    const int cl = (lane < 40) ? lane : 0;
    int r0 = blockIdx.x * 32 + wave * 8;
    r0 = __builtin_amdgcn_readfirstlane(r0);
    if (r0 >= N_NODES) return;

    float acc[8];
#pragma unroll
    for (int rr = 0; rr < 8; ++rr) acc[rr] = 0.f;
    int ridx[8];
#pragma unroll
    for (int rr = 0; rr < 8; ++rr) ridx[rr] = (r0 + rr < N_NODES) ? r0 + rr : N_NODES - 1;

    const float4* h4 = (const float4*)h;
    for (int k4 = 0; k4 < 32; ++k4) {
        float4 hr[8];
#pragma unroll
        for (int rr = 0; rr < 8; ++rr) hr[rr] = h4[ridx[rr] * 32 + k4];
#pragma unroll
        for (int j = 0; j < 4; ++j) {
            int k = k4 * 4 + j;
            float w = Wt[k][(cl + k) & 63];
#pragma unroll
            for (int rr = 0; rr < 8; ++rr) {
                float hv = (j == 0) ? hr[rr].x : (j == 1) ? hr[rr].y : (j == 2) ? hr[rr].z : hr[rr].w;
                acc[rr] = fmaf(hv, w, acc[rr]);
            }
        }
    }
    if (lane < 40) {
        float bias = b2[lane];
#pragma unroll
        for (int rr = 0; rr < 8; ++rr) {
            int r = r0 + rr;
            if (r < N_NODES) {
                float idg = 1.0f / fmaxf((float)deg_i[r], 1.0f);
                out[(size_t)r * 40 + lane] =
                    fmaf(idg, agg2[(size_t)r * 40 + lane], bias) + acc[rr];
            }
        }
    }
}

// ---------------------------------------------------------------------------
// Launch. ws layout:
//   int  deg_i[50048], cursor[50048]      (memset to 0 together)
//   int  row_ptr[50052], blk_sum[256], blk_off[256]
//   int  csr_src[800000]
//   f32  agg1[6400000]  -- z2[2000000] overlaps agg1 (agg1 dead after layer1)
//   f32  agg2[2000000]
//   f32  h[6400000]
// Total ≈ 66.9 MB.
// ---------------------------------------------------------------------------
extern "C" void kernel_launch(void* const* d_in, const int* in_sizes, int n_in,
                              void* d_out, int out_size, void* d_ws, size_t ws_size,
                              hipStream_t stream) {
    const float* x     = (const float*)d_in[0];
    const int*   ei    = (const int*)d_in[1];
    const float* W1l   = (const float*)d_in[2];
    const float* b1    = (const float*)d_in[3];
    const float* W1r   = (const float*)d_in[4];
    const float* gamma = (const float*)d_in[5];
    const float* beta  = (const float*)d_in[6];
    const float* rmean = (const float*)d_in[7];
    const float* rvar  = (const float*)d_in[8];
    const float* W2l   = (const float*)d_in[9];
    const float* b2    = (const float*)d_in[10];
    const float* W2r   = (const float*)d_in[11];
    float* out = (float*)d_out;

    int* deg_i   = (int*)d_ws;
    int* cursor  = deg_i + 50048;
    int* row_ptr = cursor + 50048;
    int* blk_sum = row_ptr + 50052;
    int* blk_off = blk_sum + 256;
    int* csr_src = blk_off + 256;
    float* agg1  = (float*)(csr_src + 800000);
    float* z2    = agg1;                 // overlap: agg1 dead after layer1
    float* agg2  = agg1 + 6400000;
    float* h     = agg2 + 2000000;

    const int* src = ei;
    const int* dst = ei + N_EDGES;

    hipMemsetAsync(deg_i, 0, (size_t)(50048 + 50048) * sizeof(int), stream);

    deg_kernel<<<(N_EDGES + 255) / 256, 256, 0, stream>>>(dst, deg_i);
    scanA_kernel<<<SCAN_BLOCKS, 256, 0, stream>>>(deg_i, row_ptr, blk_sum);
    scanB_kernel<<<1, 256, 0, stream>>>(blk_sum, blk_off);
    scanC_kernel<<<SCAN_BLOCKS, 256, 0, stream>>>(row_ptr, blk_off);
    fill_kernel<<<(N_EDGES + 255) / 256, 256, 0, stream>>>(src, dst, row_ptr, cursor, csr_src);

    gather1_kernel<<<(N_NODES + 3) / 4, 256, 0, stream>>>(csr_src, row_ptr, x, agg1);

    dim3 g1((N_NODES + 31) / 32, 2);
    layer1_kernel<<<g1, 256, 0, stream>>>(x, agg1, deg_i, W1l, b1, W1r, gamma, beta,
                                          rmean, rvar, h);

    z2_kernel<<<(N_NODES + 31) / 32, 256, 0, stream>>>(h, W2l, z2);

    gather2_kernel<<<(N_NODES + 3) / 4, 256, 0, stream>>>(csr_src, row_ptr, z2, agg2);

    final_kernel<<<(N_NODES + 31) / 32, 256, 0, stream>>>(h, W2r, agg2, deg_i, b2, out);
}

// Round 3
// 396.749 us; speedup vs baseline: 6.3236x; 2.6907x over previous
//
#include <hip/hip_runtime.h>

#define N_NODES 50000
#define N_EDGES 800000
#define N_FEAT 128
#define N_HID 128
#define N_CLS 40
#define BN_EPS 1e-5f

#define SCAN_BLOCKS ((N_NODES + 255) / 256)  // 196

// ---------------------------------------------------------------------------
// K1: int degree histogram.
// ---------------------------------------------------------------------------
__global__ __launch_bounds__(256) void deg_kernel(const int* __restrict__ dst,
                                                  int* __restrict__ deg_i) {
    int e = blockIdx.x * 256 + threadIdx.x;
    if (e < N_EDGES) atomicAdd(&deg_i[dst[e]], 1);
}

// ---------------------------------------------------------------------------
// Scan A/B/C: row_ptr = exclusive scan of degrees.
// ---------------------------------------------------------------------------
__global__ __launch_bounds__(256) void scanA_kernel(const int* __restrict__ deg_i,
                                                    int* __restrict__ row_ptr,
                                                    int* __restrict__ blk_sum) {
    __shared__ int tmp[256];
    int t = threadIdx.x;
    int i = blockIdx.x * 256 + t;
    int v = (i < N_NODES) ? deg_i[i] : 0;
    tmp[t] = v;
    __syncthreads();
    for (int off = 1; off < 256; off <<= 1) {
        int a = (t >= off) ? tmp[t - off] : 0;
        __syncthreads();
        if (t >= off) tmp[t] += a;
        __syncthreads();
    }
    if (i < N_NODES) row_ptr[i] = tmp[t] - v;
    if (t == 255) blk_sum[blockIdx.x] = tmp[255];
}

__global__ __launch_bounds__(256) void scanB_kernel(const int* __restrict__ blk_sum,
                                                    int* __restrict__ blk_off) {
    __shared__ int tmp[256];
    int t = threadIdx.x;
    int v = (t < SCAN_BLOCKS) ? blk_sum[t] : 0;
    tmp[t] = v;
    __syncthreads();
    for (int off = 1; off < 256; off <<= 1) {
        int a = (t >= off) ? tmp[t - off] : 0;
        __syncthreads();
        if (t >= off) tmp[t] += a;
        __syncthreads();
    }
    if (t < SCAN_BLOCKS) blk_off[t] = tmp[t] - v;
}

__global__ __launch_bounds__(256) void scanC_kernel(int* __restrict__ row_ptr,
                                                    const int* __restrict__ blk_off) {
    int i = blockIdx.x * 256 + threadIdx.x;
    if (i < N_NODES) row_ptr[i] += blk_off[blockIdx.x];
    if (i == 0) row_ptr[N_NODES] = N_EDGES;
}

// ---------------------------------------------------------------------------
// CSR fill.
// ---------------------------------------------------------------------------
__global__ __launch_bounds__(256) void fill_kernel(const int* __restrict__ src,
                                                   const int* __restrict__ dst,
                                                   const int* __restrict__ row_ptr,
                                                   int* __restrict__ cursor,
                                                   int* __restrict__ csr_src) {
    int e = blockIdx.x * 256 + threadIdx.x;
    if (e >= N_EDGES) return;
    int d = dst[e];
    int pos = atomicAdd(&cursor[d], 1);
    csr_src[row_ptr[d] + pos] = src[e];
}

// ---------------------------------------------------------------------------
// One-time weight transpose into k-major concat layouts:
//   WtA[k][n], k<128 -> W1l[n][k]; k>=128 -> W1r[n][k-128]   (256x128)
//   WtB[k][n], n<40 -> W2l[n][k]; 40<=n<80 -> W2r[n-40][k]; else 0  (128x128)
// ---------------------------------------------------------------------------
__global__ __launch_bounds__(256) void transposeW_kernel(
    const float* __restrict__ W1l, const float* __restrict__ W1r,
    const float* __restrict__ W2l, const float* __restrict__ W2r,
    float* __restrict__ WtA, float* __restrict__ WtB) {
    int i = blockIdx.x * 256 + threadIdx.x;
    if (i < 256 * 128) {
        int k = i >> 7, n = i & 127;
        WtA[i] = (k < 128) ? W1l[n * 128 + k] : W1r[n * 128 + (k - 128)];
    } else {
        int j = i - 256 * 128;
        if (j < 128 * 128) {
            int k = j >> 7, n = j & 127;
            WtB[j] = (n < 40) ? W2l[n * 128 + k]
                   : (n < 80) ? W2r[(n - 40) * 128 + k] : 0.0f;
        }
    }
}

// ---------------------------------------------------------------------------
// Gather-mean layer 1: wave per node, float2/lane (one 512B row per iter),
// 4x unrolled for outstanding loads. Folds inv_deg (mean) in.
// ---------------------------------------------------------------------------
__global__ __launch_bounds__(256) void gather1_kernel(const int* __restrict__ csr_src,
                                                      const int* __restrict__ row_ptr,
                                                      const float* __restrict__ x,
                                                      float* __restrict__ agg1n) {
    int gid = blockIdx.x * 4 + (threadIdx.x >> 6);
    gid = __builtin_amdgcn_readfirstlane(gid);
    int lane = threadIdx.x & 63;
    if (gid >= N_NODES) return;
    int beg = row_ptr[gid];
    int end = row_ptr[gid + 1];
    const float2* x2 = (const float2*)x;
    float2 acc = {0.f, 0.f};
    int e = beg;
    for (; e + 3 < end; e += 4) {
        int s0 = csr_src[e], s1 = csr_src[e + 1], s2 = csr_src[e + 2], s3 = csr_src[e + 3];
        float2 v0 = x2[(size_t)s0 * 64 + lane];
        float2 v1 = x2[(size_t)s1 * 64 + lane];
        float2 v2 = x2[(size_t)s2 * 64 + lane];
        float2 v3 = x2[(size_t)s3 * 64 + lane];
        acc.x += (v0.x + v1.x) + (v2.x + v3.x);
        acc.y += (v0.y + v1.y) + (v2.y + v3.y);
    }
    for (; e < end; ++e) {
        int s = csr_src[e];
        float2 v = x2[(size_t)s * 64 + lane];
        acc.x += v.x;
        acc.y += v.y;
    }
    float inv = 1.0f / fmaxf((float)(end - beg), 1.0f);
    acc.x *= inv;
    acc.y *= inv;
    ((float2*)agg1n)[(size_t)gid * 64 + lane] = acc;
}

// ---------------------------------------------------------------------------
// GEMM1: h = BN(ReLU(agg1n @ W1l^T + b1 + x @ W1r^T))
// Register-tiled f32 GEMM: 256 thr, macro 64x128, micro 8x4 (32 acc),
// K = 2 phases x 128, chunks of 32 staged k-major in LDS.
//   As[kk][m]  (+4 pad): inner reads are 2-address broadcast b128
//   Ws[kk][n]  (+4 pad): inner reads are conflict-free b128
// LDS 25.6 KB -> 6 blocks/CU.
// ---------------------------------------------------------------------------
__global__ __launch_bounds__(256) void gemm1_kernel(
    const float* __restrict__ agg1n, const float* __restrict__ x,
    const float* __restrict__ WtA, const float* __restrict__ b1,
    const float* __restrict__ gamma, const float* __restrict__ beta,
    const float* __restrict__ rmean, const float* __restrict__ rvar,
    float* __restrict__ h) {
    __shared__ float As[32][68];
    __shared__ float Ws[32][132];
    const int t = threadIdx.x;
    const int cg = t & 31;   // col group: cols cg*4 .. cg*4+3
    const int rg = t >> 5;   // row group: rows rg*8 .. rg*8+7
    const int mbase = blockIdx.x * 64;

    float acc[8][4];
#pragma unroll
    for (int i = 0; i < 8; ++i)
#pragma unroll
        for (int j = 0; j < 4; ++j) acc[i][j] = 0.f;

    for (int phase = 0; phase < 2; ++phase) {
        const float* __restrict__ A = phase ? x : agg1n;
        for (int kc = 0; kc < 4; ++kc) {
            const int kb = kc * 32;            // k base within phase
            const int kw = phase * 128 + kb;   // row base in WtA
            __syncthreads();
            // stage A chunk (64 rows x 32 k), transposed to k-major
#pragma unroll
            for (int j = 0; j < 8; ++j) {
                int e = j * 256 + t;
                int kk = e & 31, m = e >> 5;
                int row = mbase + m;
                As[kk][m] = (row < N_NODES) ? A[(size_t)row * 128 + kb + kk] : 0.f;
            }
            // stage W chunk (32 k x 128 n), already k-major
#pragma unroll
            for (int j = 0; j < 16; ++j) {
                int e = j * 256 + t;
                int c = e & 127, kk = e >> 7;
                Ws[kk][c] = WtA[(size_t)(kw + kk) * 128 + c];
            }
            __syncthreads();
#pragma unroll
            for (int kk = 0; kk < 32; ++kk) {
                float4 w = *(const float4*)&Ws[kk][cg * 4];
                float4 a0 = *(const float4*)&As[kk][rg * 8];
                float4 a1 = *(const float4*)&As[kk][rg * 8 + 4];
                acc[0][0] = fmaf(a0.x, w.x, acc[0][0]); acc[0][1] = fmaf(a0.x, w.y, acc[0][1]);
                acc[0][2] = fmaf(a0.x, w.z, acc[0][2]); acc[0][3] = fmaf(a0.x, w.w, acc[0][3]);
                acc[1][0] = fmaf(a0.y, w.x, acc[1][0]); acc[1][1] = fmaf(a0.y, w.y, acc[1][1]);
                acc[1][2] = fmaf(a0.y, w.z, acc[1][2]); acc[1][3] = fmaf(a0.y, w.w, acc[1][3]);
                acc[2][0] = fmaf(a0.z, w.x, acc[2][0]); acc[2][1] = fmaf(a0.z, w.y, acc[2][1]);
                acc[2][2] = fmaf(a0.z, w.z, acc[2][2]); acc[2][3] = fmaf(a0.z, w.w, acc[2][3]);
                acc[3][0] = fmaf(a0.w, w.x, acc[3][0]); acc[3][1] = fmaf(a0.w, w.y, acc[3][1]);
                acc[3][2] = fmaf(a0.w, w.z, acc[3][2]); acc[3][3] = fmaf(a0.w, w.w, acc[3][3]);
                acc[4][0] = fmaf(a1.x, w.x, acc[4][0]); acc[4][1] = fmaf(a1.x, w.y, acc[4][1]);
                acc[4][2] = fmaf(a1.x, w.z, acc[4][2]); acc[4][3] = fmaf(a1.x, w.w, acc[4][3]);
                acc[5][0] = fmaf(a1.y, w.x, acc[5][0]); acc[5][1] = fmaf(a1.y, w.y, acc[5][1]);
                acc[5][2] = fmaf(a1.y, w.z, acc[5][2]); acc[5][3] = fmaf(a1.y, w.w, acc[5][3]);
                acc[6][0] = fmaf(a1.z, w.x, acc[6][0]); acc[6][1] = fmaf(a1.z, w.y, acc[6][1]);
                acc[6][2] = fmaf(a1.z, w.z, acc[6][2]); acc[6][3] = fmaf(a1.z, w.w, acc[6][3]);
                acc[7][0] = fmaf(a1.w, w.x, acc[7][0]); acc[7][1] = fmaf(a1.w, w.y, acc[7][1]);
                acc[7][2] = fmaf(a1.w, w.z, acc[7][2]); acc[7][3] = fmaf(a1.w, w.w, acc[7][3]);
            }
        }
    }

    // epilogue: bias + ReLU + BN (eval stats), fused
    const int c0 = cg * 4;
    float4 bi = *(const float4*)&b1[c0];
    float4 ga = *(const float4*)&gamma[c0];
    float4 be = *(const float4*)&beta[c0];
    float4 rm = *(const float4*)&rmean[c0];
    float4 rv = *(const float4*)&rvar[c0];
    float sc[4], sh[4], bb[4] = {bi.x, bi.y, bi.z, bi.w};
    sc[0] = ga.x * rsqrtf(rv.x + BN_EPS); sh[0] = fmaf(-rm.x, sc[0], be.x);
    sc[1] = ga.y * rsqrtf(rv.y + BN_EPS); sh[1] = fmaf(-rm.y, sc[1], be.y);
    sc[2] = ga.z * rsqrtf(rv.z + BN_EPS); sh[2] = fmaf(-rm.z, sc[2], be.z);
    sc[3] = ga.w * rsqrtf(rv.w + BN_EPS); sh[3] = fmaf(-rm.w, sc[3], be.w);
#pragma unroll
    for (int i = 0; i < 8; ++i) {
        int row = mbase + rg * 8 + i;
        if (row < N_NODES) {
            float4 r4;
            r4.x = fmaf(fmaxf(acc[i][0] + bb[0], 0.f), sc[0], sh[0]);
            r4.y = fmaf(fmaxf(acc[i][1] + bb[1], 0.f), sc[1], sh[1]);
            r4.z = fmaf(fmaxf(acc[i][2] + bb[2], 0.f), sc[2], sh[2]);
            r4.w = fmaf(fmaxf(acc[i][3] + bb[3], 0.f), sc[3], sh[3]);
            *(float4*)&h[(size_t)row * 128 + c0] = r4;
        }
    }
}

// ---------------------------------------------------------------------------
// GEMM2: ZP = h @ WtB   (cols 0..39 = h@W2l^T, 40..79 = h@W2r^T, rest 0)
// Same structure, K=128 single phase, plain store.
// ---------------------------------------------------------------------------
__global__ __launch_bounds__(256) void gemm2_kernel(const float* __restrict__ h,
                                                    const float* __restrict__ WtB,
                                                    float* __restrict__ ZP) {
    __shared__ float As[32][68];
    __shared__ float Ws[32][132];
    const int t = threadIdx.x;
    const int cg = t & 31;
    const int rg = t >> 5;
    const int mbase = blockIdx.x * 64;

    float acc[8][4];
#pragma unroll
    for (int i = 0; i < 8; ++i)
#pragma unroll
        for (int j = 0; j < 4; ++j) acc[i][j] = 0.f;

    for (int kc = 0; kc < 4; ++kc) {
        const int kb = kc * 32;
        __syncthreads();
#pragma unroll
        for (int j = 0; j < 8; ++j) {
            int e = j * 256 + t;
            int kk = e & 31, m = e >> 5;
            int row = mbase + m;
            As[kk][m] = (row < N_NODES) ? h[(size_t)row * 128 + kb + kk] : 0.f;
        }
#pragma unroll
        for (int j = 0; j < 16; ++j) {
            int e = j * 256 + t;
            int c = e & 127, kk = e >> 7;
            Ws[kk][c] = WtB[(size_t)(kb + kk) * 128 + c];
        }
        __syncthreads();
#pragma unroll
        for (int kk = 0; kk < 32; ++kk) {
            float4 w = *(const float4*)&Ws[kk][cg * 4];
            float4 a0 = *(const float4*)&As[kk][rg * 8];
            float4 a1 = *(const float4*)&As[kk][rg * 8 + 4];
            acc[0][0] = fmaf(a0.x, w.x, acc[0][0]); acc[0][1] = fmaf(a0.x, w.y, acc[0][1]);
            acc[0][2] = fmaf(a0.x, w.z, acc[0][2]); acc[0][3] = fmaf(a0.x, w.w, acc[0][3]);
            acc[1][0] = fmaf(a0.y, w.x, acc[1][0]); acc[1][1] = fmaf(a0.y, w.y, acc[1][1]);
            acc[1][2] = fmaf(a0.y, w.z, acc[1][2]); acc[1][3] = fmaf(a0.y, w.w, acc[1][3]);
            acc[2][0] = fmaf(a0.z, w.x, acc[2][0]); acc[2][1] = fmaf(a0.z, w.y, acc[2][1]);
            acc[2][2] = fmaf(a0.z, w.z, acc[2][2]); acc[2][3] = fmaf(a0.z, w.w, acc[2][3]);
            acc[3][0] = fmaf(a0.w, w.x, acc[3][0]); acc[3][1] = fmaf(a0.w, w.y, acc[3][1]);
            acc[3][2] = fmaf(a0.w, w.z, acc[3][2]); acc[3][3] = fmaf(a0.w, w.w, acc[3][3]);
            acc[4][0] = fmaf(a1.x, w.x, acc[4][0]); acc[4][1] = fmaf(a1.x, w.y, acc[4][1]);
            acc[4][2] = fmaf(a1.x, w.z, acc[4][2]); acc[4][3] = fmaf(a1.x, w.w, acc[4][3]);
            acc[5][0] = fmaf(a1.y, w.x, acc[5][0]); acc[5][1] = fmaf(a1.y, w.y, acc[5][1]);
            acc[5][2] = fmaf(a1.y, w.z, acc[5][2]); acc[5][3] = fmaf(a1.y, w.w, acc[5][3]);
            acc[6][0] = fmaf(a1.z, w.x, acc[6][0]); acc[6][1] = fmaf(a1.z, w.y, acc[6][1]);
            acc[6][2] = fmaf(a1.z, w.z, acc[6][2]); acc[6][3] = fmaf(a1.z, w.w, acc[6][3]);
            acc[7][0] = fmaf(a1.w, w.x, acc[7][0]); acc[7][1] = fmaf(a1.w, w.y, acc[7][1]);
            acc[7][2] = fmaf(a1.w, w.z, acc[7][2]); acc[7][3] = fmaf(a1.w, w.w, acc[7][3]);
        }
    }

    const int c0 = cg * 4;
#pragma unroll
    for (int i = 0; i < 8; ++i) {
        int row = mbase + rg * 8 + i;
        if (row < N_NODES) {
            float4 r4 = {acc[i][0], acc[i][1], acc[i][2], acc[i][3]};
            *(float4*)&ZP[(size_t)row * 128 + c0] = r4;
        }
    }
}

// ---------------------------------------------------------------------------
// Gather layer 2 + final: out = mean_s(ZP[s][0:40]) + ZP[r][40:80] + b2
// ---------------------------------------------------------------------------
__global__ __launch_bounds__(256) void gather2_kernel(const int* __restrict__ csr_src,
                                                      const int* __restrict__ row_ptr,
                                                      const float* __restrict__ ZP,
                                                      const float* __restrict__ b2,
                                                      float* __restrict__ out) {
    int gid = blockIdx.x * 4 + (threadIdx.x >> 6);
    gid = __builtin_amdgcn_readfirstlane(gid);
    int lane = threadIdx.x & 63;
    if (gid >= N_NODES) return;
    int beg = row_ptr[gid];
    int end = row_ptr[gid + 1];
    float acc = 0.f;
    int e = beg;
    for (; e + 3 < end; e += 4) {
        int s0 = csr_src[e], s1 = csr_src[e + 1], s2 = csr_src[e + 2], s3 = csr_src[e + 3];
        float v0 = ZP[(size_t)s0 * 128 + lane];
        float v1 = ZP[(size_t)s1 * 128 + lane];
        float v2 = ZP[(size_t)s2 * 128 + lane];
        float v3 = ZP[(size_t)s3 * 128 + lane];
        acc += (v0 + v1) + (v2 + v3);
    }
    for (; e < end; ++e) {
        acc += ZP[(size_t)csr_src[e] * 128 + lane];
    }
    if (lane < 40) {
        float inv = 1.0f / fmaxf((float)(end - beg), 1.0f);
        out[(size_t)gid * 40 + lane] =
            fmaf(acc, inv, ZP[(size_t)gid * 128 + 40 + lane] + b2[lane]);
    }
}

// ---------------------------------------------------------------------------
// Launch. ws layout:
//   int  deg_i[50048], cursor[50048]          (memset 0 together)
//   int  row_ptr[50052], blk_sum[256], blk_off[256]
//   int  csr_src[800000]
//   f32  WtA[32768], WtB[16384]
//   f32  agg1n[50048*128]   -- ZP aliases this (agg1n dead after gemm1)
//   f32  h[50048*128]
// Total ~55.3 MB.
// ---------------------------------------------------------------------------
extern "C" void kernel_launch(void* const* d_in, const int* in_sizes, int n_in,
                              void* d_out, int out_size, void* d_ws, size_t ws_size,
                              hipStream_t stream) {
    const float* x     = (const float*)d_in[0];
    const int*   ei    = (const int*)d_in[1];
    const float* W1l   = (const float*)d_in[2];
    const float* b1    = (const float*)d_in[3];
    const float* W1r   = (const float*)d_in[4];
    const float* gamma = (const float*)d_in[5];
    const float* beta  = (const float*)d_in[6];
    const float* rmean = (const float*)d_in[7];
    const float* rvar  = (const float*)d_in[8];
    const float* W2l   = (const float*)d_in[9];
    const float* b2    = (const float*)d_in[10];
    const float* W2r   = (const float*)d_in[11];
    float* out = (float*)d_out;

    int* deg_i   = (int*)d_ws;
    int* cursor  = deg_i + 50048;
    int* row_ptr = cursor + 50048;
    int* blk_sum = row_ptr + 50052;
    int* blk_off = blk_sum + 256;
    int* csr_src = blk_off + 256;
    float* WtA   = (float*)(csr_src + 800000);
    float* WtB   = WtA + 32768;
    float* agg1n = WtB + 16384;
    float* ZP    = agg1n;  // alias: agg1n dead after gemm1
    float* h     = agg1n + (size_t)50048 * 128;

    const int* src = ei;
    const int* dst = ei + N_EDGES;

    hipMemsetAsync(deg_i, 0, (size_t)(50048 + 50048) * sizeof(int), stream);

    deg_kernel<<<(N_EDGES + 255) / 256, 256, 0, stream>>>(dst, deg_i);
    scanA_kernel<<<SCAN_BLOCKS, 256, 0, stream>>>(deg_i, row_ptr, blk_sum);
    scanB_kernel<<<1, 256, 0, stream>>>(blk_sum, blk_off);
    scanC_kernel<<<SCAN_BLOCKS, 256, 0, stream>>>(row_ptr, blk_off);
    fill_kernel<<<(N_EDGES + 255) / 256, 256, 0, stream>>>(src, dst, row_ptr, cursor, csr_src);

    transposeW_kernel<<<192, 256, 0, stream>>>(W1l, W1r, W2l, W2r, WtA, WtB);

    gather1_kernel<<<(N_NODES + 3) / 4, 256, 0, stream>>>(csr_src, row_ptr, x, agg1n);

    gemm1_kernel<<<(N_NODES + 63) / 64, 256, 0, stream>>>(agg1n, x, WtA, b1, gamma,
                                                          beta, rmean, rvar, h);

    gemm2_kernel<<<(N_NODES + 63) / 64, 256, 0, stream>>>(h, WtB, ZP);

    gather2_kernel<<<(N_NODES + 3) / 4, 256, 0, stream>>>(csr_src, row_ptr, ZP, b2, out);
}

// Round 4
// 365.169 us; speedup vs baseline: 6.8704x; 1.0865x over previous
//
#include <hip/hip_runtime.h>

#define N_NODES 50000
#define N_EDGES 800000
#define N_FEAT 128
#define N_HID 128
#define N_CLS 40
#define BN_EPS 1e-5f

#define SCAN_BLOCKS ((N_NODES + 255) / 256)  // 196

// ---------------------------------------------------------------------------
// K1: int degree histogram.
// ---------------------------------------------------------------------------
__global__ __launch_bounds__(256) void deg_kernel(const int* __restrict__ dst,
                                                  int* __restrict__ deg_i) {
    int e = blockIdx.x * 256 + threadIdx.x;
    if (e < N_EDGES) atomicAdd(&deg_i[dst[e]], 1);
}

// ---------------------------------------------------------------------------
// Scan A/B/C: row_ptr = exclusive scan of degrees.
// ---------------------------------------------------------------------------
__global__ __launch_bounds__(256) void scanA_kernel(const int* __restrict__ deg_i,
                                                    int* __restrict__ row_ptr,
                                                    int* __restrict__ blk_sum) {
    __shared__ int tmp[256];
    int t = threadIdx.x;
    int i = blockIdx.x * 256 + t;
    int v = (i < N_NODES) ? deg_i[i] : 0;
    tmp[t] = v;
    __syncthreads();
    for (int off = 1; off < 256; off <<= 1) {
        int a = (t >= off) ? tmp[t - off] : 0;
        __syncthreads();
        if (t >= off) tmp[t] += a;
        __syncthreads();
    }
    if (i < N_NODES) row_ptr[i] = tmp[t] - v;
    if (t == 255) blk_sum[blockIdx.x] = tmp[255];
}

__global__ __launch_bounds__(256) void scanB_kernel(const int* __restrict__ blk_sum,
                                                    int* __restrict__ blk_off) {
    __shared__ int tmp[256];
    int t = threadIdx.x;
    int v = (t < SCAN_BLOCKS) ? blk_sum[t] : 0;
    tmp[t] = v;
    __syncthreads();
    for (int off = 1; off < 256; off <<= 1) {
        int a = (t >= off) ? tmp[t - off] : 0;
        __syncthreads();
        if (t >= off) tmp[t] += a;
        __syncthreads();
    }
    if (t < SCAN_BLOCKS) blk_off[t] = tmp[t] - v;
}

__global__ __launch_bounds__(256) void scanC_kernel(int* __restrict__ row_ptr,
                                                    const int* __restrict__ blk_off) {
    int i = blockIdx.x * 256 + threadIdx.x;
    if (i < N_NODES) row_ptr[i] += blk_off[blockIdx.x];
    if (i == 0) row_ptr[N_NODES] = N_EDGES;
}

// ---------------------------------------------------------------------------
// CSR fill.
// ---------------------------------------------------------------------------
__global__ __launch_bounds__(256) void fill_kernel(const int* __restrict__ src,
                                                   const int* __restrict__ dst,
                                                   const int* __restrict__ row_ptr,
                                                   int* __restrict__ cursor,
                                                   int* __restrict__ csr_src) {
    int e = blockIdx.x * 256 + threadIdx.x;
    if (e >= N_EDGES) return;
    int d = dst[e];
    int pos = atomicAdd(&cursor[d], 1);
    csr_src[row_ptr[d] + pos] = src[e];
}

// ---------------------------------------------------------------------------
// Weight transpose to k-major:
//   WtA[k][n] 256x128: k<128 -> W1l[n][k]; else W1r[n][k-128]
//   WtB[k][n] 128x96 : n<40 -> W2l[n][k]; n<80 -> W2r[n-40][k]; else 0
// ---------------------------------------------------------------------------
__global__ __launch_bounds__(256) void transposeW_kernel(
    const float* __restrict__ W1l, const float* __restrict__ W1r,
    const float* __restrict__ W2l, const float* __restrict__ W2r,
    float* __restrict__ WtA, float* __restrict__ WtB) {
    int i = blockIdx.x * 256 + threadIdx.x;
    if (i < 256 * 128) {
        int k = i >> 7, n = i & 127;
        WtA[i] = (k < 128) ? W1l[n * 128 + k] : W1r[n * 128 + (k - 128)];
    } else {
        int j = i - 256 * 128;
        if (j < 128 * 96) {
            int k = j / 96, n = j % 96;
            WtB[j] = (n < 40) ? W2l[n * 128 + k]
                   : (n < 80) ? W2r[(n - 40) * 128 + k] : 0.0f;
        }
    }
}

// ---------------------------------------------------------------------------
// Gather-mean layer 1: wave per node; 2 edges per iter (one per half-wave),
// float4 per lane (wave fetches 1 KB/iter), 3x unrolled -> 6 edges in flight.
// Folds inv_deg (mean). Cross-half combine via shuffle.
// ---------------------------------------------------------------------------
__global__ __launch_bounds__(256) void gather1_kernel(const int* __restrict__ csr_src,
                                                      const int* __restrict__ row_ptr,
                                                      const float* __restrict__ x,
                                                      float* __restrict__ agg1n) {
    int gid = __builtin_amdgcn_readfirstlane(blockIdx.x * 4 + (threadIdx.x >> 6));
    if (gid >= N_NODES) return;
    int lane = threadIdx.x & 63;
    int half = lane >> 5;
    int li = lane & 31;
    int beg = row_ptr[gid], end = row_ptr[gid + 1];
    const float4* x4 = (const float4*)x;
    float4 acc = {0.f, 0.f, 0.f, 0.f};
    int e = beg + half;
    for (; e + 4 < end; e += 6) {
        int s0 = csr_src[e], s1 = csr_src[e + 2], s2 = csr_src[e + 4];
        float4 v0 = x4[(size_t)s0 * 32 + li];
        float4 v1 = x4[(size_t)s1 * 32 + li];
        float4 v2 = x4[(size_t)s2 * 32 + li];
        acc.x += v0.x + v1.x + v2.x;
        acc.y += v0.y + v1.y + v2.y;
        acc.z += v0.z + v1.z + v2.z;
        acc.w += v0.w + v1.w + v2.w;
    }
    for (; e < end; e += 2) {
        int s = csr_src[e];
        float4 v = x4[(size_t)s * 32 + li];
        acc.x += v.x; acc.y += v.y; acc.z += v.z; acc.w += v.w;
    }
    float4 o;
    o.x = __shfl(acc.x, lane ^ 32);
    o.y = __shfl(acc.y, lane ^ 32);
    o.z = __shfl(acc.z, lane ^ 32);
    o.w = __shfl(acc.w, lane ^ 32);
    if (half == 0) {
        float inv = 1.0f / fmaxf((float)(end - beg), 1.0f);
        float4 r;
        r.x = (acc.x + o.x) * inv;
        r.y = (acc.y + o.y) * inv;
        r.z = (acc.z + o.z) * inv;
        r.w = (acc.w + o.w) * inv;
        ((float4*)agg1n)[(size_t)gid * 32 + li] = r;
    }
}

// ---------------------------------------------------------------------------
// GEMM1: h = BN(ReLU(agg1n @ W1l^T + b1 + x @ W1r^T))
// LDS-free GEMM: lane = row (A from global, L1-resident: 4 waves x 64 rows x
// 64B line = 16KB), weights k-major -> wave-uniform scalar loads feeding
// v_fmac SGPR operand. Wave = 64 rows x 32 cols, 32 acc. No barriers.
// Grid (196, 4): y = 32-col block.
// ---------------------------------------------------------------------------
__global__ __launch_bounds__(256) void gemm1_kernel(
    const float* __restrict__ agg1n, const float* __restrict__ x,
    const float* __restrict__ WtA, const float* __restrict__ b1,
    const float* __restrict__ gamma, const float* __restrict__ beta,
    const float* __restrict__ rmean, const float* __restrict__ rvar,
    float* __restrict__ h) {
    const int wid = __builtin_amdgcn_readfirstlane(threadIdx.x >> 6);
    const int lane = threadIdx.x & 63;
    const int row = blockIdx.x * 256 + wid * 64 + lane;
    const int c0 = blockIdx.y * 32;
    const bool valid = row < N_NODES;
    const int rowc = valid ? row : N_NODES - 1;

    float acc[32];
#pragma unroll
    for (int c = 0; c < 32; ++c) acc[c] = 0.f;

#pragma unroll
    for (int phase = 0; phase < 2; ++phase) {
        const float* __restrict__ A = phase ? x : agg1n;
        const float4* __restrict__ Arow = (const float4*)(A + (size_t)rowc * 128);
        const float* __restrict__ Wb = WtA + (size_t)(phase * 128) * 128 + c0;
#pragma unroll 4
        for (int k4 = 0; k4 < 32; ++k4) {
            float4 a4 = Arow[k4];
#pragma unroll
            for (int j = 0; j < 4; ++j) {
                float av = (j == 0) ? a4.x : (j == 1) ? a4.y : (j == 2) ? a4.z : a4.w;
                const float* __restrict__ Wr = Wb + (size_t)(k4 * 4 + j) * 128;
#pragma unroll
                for (int c = 0; c < 32; ++c) acc[c] = fmaf(av, Wr[c], acc[c]);
            }
        }
    }

    if (!valid) return;
    float* hrow = h + (size_t)row * 128 + c0;
#pragma unroll
    for (int q = 0; q < 8; ++q) {
        float4 r;
        float rs[4];
#pragma unroll
        for (int u = 0; u < 4; ++u) {
            int c = q * 4 + u;
            float sc = gamma[c0 + c] * rsqrtf(rvar[c0 + c] + BN_EPS);
            float sh = fmaf(-rmean[c0 + c], sc, beta[c0 + c]);
            float pre = acc[c] + b1[c0 + c];
            rs[u] = fmaf(fmaxf(pre, 0.f), sc, sh);
        }
        r.x = rs[0]; r.y = rs[1]; r.z = rs[2]; r.w = rs[3];
        *(float4*)(hrow + q * 4) = r;
    }
}

// ---------------------------------------------------------------------------
// GEMM2: [z2 | p2] = h @ WtB   (cols 0..39 -> z2 stride 48, 40..79 -> p2
// stride 40, 80..95 computed-and-discarded). Same LDS-free structure, K=128.
// Grid (196, 3).
// ---------------------------------------------------------------------------
__global__ __launch_bounds__(256) void gemm2_kernel(const float* __restrict__ h,
                                                    const float* __restrict__ WtB,
                                                    float* __restrict__ z2,
                                                    float* __restrict__ p2) {
    const int wid = __builtin_amdgcn_readfirstlane(threadIdx.x >> 6);
    const int lane = threadIdx.x & 63;
    const int row = blockIdx.x * 256 + wid * 64 + lane;
    const int c0 = blockIdx.y * 32;
    const bool valid = row < N_NODES;
    const int rowc = valid ? row : N_NODES - 1;

    float acc[32];
#pragma unroll
    for (int c = 0; c < 32; ++c) acc[c] = 0.f;

    const float4* __restrict__ Arow = (const float4*)(h + (size_t)rowc * 128);
    const float* __restrict__ Wb = WtB + c0;
#pragma unroll 4
    for (int k4 = 0; k4 < 32; ++k4) {
        float4 a4 = Arow[k4];
#pragma unroll
        for (int j = 0; j < 4; ++j) {
            float av = (j == 0) ? a4.x : (j == 1) ? a4.y : (j == 2) ? a4.z : a4.w;
            const float* __restrict__ Wr = Wb + (size_t)(k4 * 4 + j) * 96;
#pragma unroll
            for (int c = 0; c < 32; ++c) acc[c] = fmaf(av, Wr[c], acc[c]);
        }
    }

    if (!valid) return;
#pragma unroll
    for (int q = 0; q < 8; ++q) {
        int cg = c0 + q * 4;
        float4 r = {acc[q * 4], acc[q * 4 + 1], acc[q * 4 + 2], acc[q * 4 + 3]};
        if (cg < 40) {
            *(float4*)(z2 + (size_t)row * 48 + cg) = r;
        } else if (cg < 80) {
            *(float4*)(p2 + (size_t)row * 40 + (cg - 40)) = r;
        }
    }
}

// ---------------------------------------------------------------------------
// Gather layer 2 + final: out = mean_s(z2[s]) + p2[r] + b2
// Wave per node, 5 edges/iter: lanes grouped 12/edge, float4/lane over
// stride-48 z2 rows (pad cols 40..47 read-and-discarded). Shuffle-reduce the
// 5 sub-groups, lanes 0..9 write the 40-col output row.
// ---------------------------------------------------------------------------
__global__ __launch_bounds__(256) void gather2_kernel(const int* __restrict__ csr_src,
                                                      const int* __restrict__ row_ptr,
                                                      const float* __restrict__ z2,
                                                      const float* __restrict__ p2,
                                                      const float* __restrict__ b2,
                                                      float* __restrict__ out) {
    int gid = __builtin_amdgcn_readfirstlane(blockIdx.x * 4 + (threadIdx.x >> 6));
    if (gid >= N_NODES) return;
    int lane = threadIdx.x & 63;
    int sub = lane / 12;          // 0..5 (5 = inactive)
    int li = lane - sub * 12;     // 0..11
    bool active = sub < 5;
    int beg = row_ptr[gid], end = row_ptr[gid + 1];
    int n = end - beg;
    const float4* z4 = (const float4*)z2;
    float4 acc = {0.f, 0.f, 0.f, 0.f};
    int iters = (n + 4) / 5;
    int e = beg + sub;
    for (int it = 0; it < iters; ++it, e += 5) {
        bool v = active && (e < end);
        int ee = v ? e : beg;
        int s = csr_src[ee];
        float4 t = z4[(size_t)s * 12 + li];
        if (v) {
            acc.x += t.x; acc.y += t.y; acc.z += t.z; acc.w += t.w;
        }
    }
    float4 a0 = acc;
#pragma unroll
    for (int k = 1; k <= 4; ++k) {
        float4 t;
        t.x = __shfl(a0.x, lane + 12 * k);
        t.y = __shfl(a0.y, lane + 12 * k);
        t.z = __shfl(a0.z, lane + 12 * k);
        t.w = __shfl(a0.w, lane + 12 * k);
        acc.x += t.x; acc.y += t.y; acc.z += t.z; acc.w += t.w;
    }
    if (sub == 0 && li < 10) {
        float inv = 1.0f / fmaxf((float)n, 1.0f);
        float4 p = ((const float4*)p2)[(size_t)gid * 10 + li];
        float4 bb = ((const float4*)b2)[li];
        float4 r;
        r.x = fmaf(acc.x, inv, p.x + bb.x);
        r.y = fmaf(acc.y, inv, p.y + bb.y);
        r.z = fmaf(acc.z, inv, p.z + bb.z);
        r.w = fmaf(acc.w, inv, p.w + bb.w);
        ((float4*)out)[(size_t)gid * 10 + li] = r;
    }
}

// ---------------------------------------------------------------------------
// Launch. ws layout:
//   int  deg_i[50048], cursor[50048]          (memset 0 together)
//   int  row_ptr[50052], blk_sum[256], blk_off[256], csr_src[800000]
//   f32  WtA[32768], WtB[12288]
//   f32  agg1n[50048*128]   -- z2[50048*48] + p2[50048*40] alias this region
//   f32  h[50048*128]
// Total ~55.3 MB.
// ---------------------------------------------------------------------------
extern "C" void kernel_launch(void* const* d_in, const int* in_sizes, int n_in,
                              void* d_out, int out_size, void* d_ws, size_t ws_size,
                              hipStream_t stream) {
    const float* x     = (const float*)d_in[0];
    const int*   ei    = (const int*)d_in[1];
    const float* W1l   = (const float*)d_in[2];
    const float* b1    = (const float*)d_in[3];
    const float* W1r   = (const float*)d_in[4];
    const float* gamma = (const float*)d_in[5];
    const float* beta  = (const float*)d_in[6];
    const float* rmean = (const float*)d_in[7];
    const float* rvar  = (const float*)d_in[8];
    const float* W2l   = (const float*)d_in[9];
    const float* b2    = (const float*)d_in[10];
    const float* W2r   = (const float*)d_in[11];
    float* out = (float*)d_out;

    int* deg_i   = (int*)d_ws;
    int* cursor  = deg_i + 50048;
    int* row_ptr = cursor + 50048;
    int* blk_sum = row_ptr + 50052;
    int* blk_off = blk_sum + 256;
    int* csr_src = blk_off + 256;
    float* WtA   = (float*)(csr_src + 800000);
    float* WtB   = WtA + 32768;
    float* agg1n = WtB + 12288;
    float* z2    = agg1n;                       // alias (agg1n dead after gemm1)
    float* p2    = z2 + (size_t)50048 * 48;
    float* h     = agg1n + (size_t)50048 * 128;

    const int* src = ei;
    const int* dst = ei + N_EDGES;

    hipMemsetAsync(deg_i, 0, (size_t)(50048 + 50048) * sizeof(int), stream);

    deg_kernel<<<(N_EDGES + 255) / 256, 256, 0, stream>>>(dst, deg_i);
    scanA_kernel<<<SCAN_BLOCKS, 256, 0, stream>>>(deg_i, row_ptr, blk_sum);
    scanB_kernel<<<1, 256, 0, stream>>>(blk_sum, blk_off);
    scanC_kernel<<<SCAN_BLOCKS, 256, 0, stream>>>(row_ptr, blk_off);
    fill_kernel<<<(N_EDGES + 255) / 256, 256, 0, stream>>>(src, dst, row_ptr, cursor, csr_src);

    transposeW_kernel<<<176, 256, 0, stream>>>(W1l, W1r, W2l, W2r, WtA, WtB);

    gather1_kernel<<<(N_NODES + 3) / 4, 256, 0, stream>>>(csr_src, row_ptr, x, agg1n);

    dim3 g1((N_NODES + 255) / 256, 4);
    gemm1_kernel<<<g1, 256, 0, stream>>>(agg1n, x, WtA, b1, gamma, beta, rmean, rvar, h);

    dim3 g2((N_NODES + 255) / 256, 3);
    gemm2_kernel<<<g2, 256, 0, stream>>>(h, WtB, z2, p2);

    gather2_kernel<<<(N_NODES + 3) / 4, 256, 0, stream>>>(csr_src, row_ptr, z2, p2, b2, out);
}